// Round 1
// 1560.845 us; speedup vs baseline: 1.1836x; 1.1836x over previous
//
#include <hip/hip_runtime.h>

#define DHN 512
#define TN  1024
#define BN  64
#define CH  32      // noise-staging chunk (steps)

static __device__ __forceinline__ float sigm(float x) {
  return 1.0f / (1.0f + __expf(-x));
}

#if defined(__has_builtin)
#if __has_builtin(__builtin_amdgcn_sdot4)
#define HAVE_SDOT4 1
#endif
#endif

// All packed bytes are in [0,127]: signed == unsigned dot.
static __device__ __forceinline__ int dot4(int a, int b, int c) {
#ifdef HAVE_SDOT4
  return __builtin_amdgcn_sdot4(a, b, c, false);
#else
  c += (int)(signed char)(a)       * (int)(signed char)(b);
  c += (int)(signed char)(a >> 8)  * (int)(signed char)(b >> 8);
  c += (int)(signed char)(a >> 16) * (int)(signed char)(b >> 16);
  c += (int)(signed char)(a >> 24) * (int)(signed char)(b >> 24);
  return c;
#endif
}

// lgkm-only step barrier: orders the rbuf LDS producer->consumer handoff
// WITHOUT draining vmcnt (keeps noise-prefetch loads + xs stores in flight).
// sched_barrier(0) fences stop the compiler from hoisting LDS ops across
// the asm (guide rule #18).
static __device__ __forceinline__ void lds_barrier() {
  __builtin_amdgcn_sched_barrier(0);
  asm volatile("s_waitcnt lgkmcnt(0)\n\ts_barrier" ::: "memory");
  __builtin_amdgcn_sched_barrier(0);
}

// Persistent RNN: one block per batch chain (64 blocks, 64 CUs). Thread h
// owns row h of W = |_w|, quantized i8 (per-row scale) into 128 VGPRs.
// r-vector distribution per step: each wave does ONE per-lane ds_read_b64
// (512 B total) and broadcasts the 128 words via v_readlane -> SGPR ->
// v_dot4. This replaces 32 broadcast ds_read_b128 per wave per step
// (256 LDS-pipe instr/CU/step -> 16), which the counters show was the
// serializing resource. Noise is prefetched per-chunk into VGPRs and
// spilled to LDS at chunk boundaries (T14); per-step barriers are
// lgkm-only so those loads stay in flight.
__global__ __launch_bounds__(512) void k_rnn(
    const float* __restrict__ u, const float* __restrict__ r0,
    const float* __restrict__ noise, const float* __restrict__ win,
    const float* __restrict__ taus, const float* __restrict__ wmat,
    float* __restrict__ xs) {
  __shared__ float u_lds[TN];                       // 4 KB
  __shared__ float nz_lds[CH * DHN];                // 64 KB
  __shared__ __align__(16) signed char rbuf[2][DHN]; // 1 KB, i8 r dbuf

  const int h = threadIdx.x;
  const int lane = h & 63;
  const int b = blockIdx.x;
  const float* wrow = wmat + h * DHN;   // row h of _w (2 KB, 16B-aligned)

  // pass 1: row absmax of |_w[h,:]|
  float rmax = 1e-30f;
#pragma unroll 8
  for (int k = 0; k < 128; ++k) {
    float4 v = *(const float4*)(wrow + 4 * k);
    rmax = fmaxf(rmax, fabsf(v.x));
    rmax = fmaxf(rmax, fabsf(v.y));
    rmax = fmaxf(rmax, fabsf(v.z));
    rmax = fmaxf(rmax, fabsf(v.w));
  }
  const float qs = 127.0f / rmax;

  // pass 2: quantize row into 128 VGPRs; w[k] bytes 0..3 = |w| cols 4k..4k+3
  int w[128];
#pragma unroll
  for (int k = 0; k < 128; ++k) {
    float4 v = *(const float4*)(wrow + 4 * k);
    int q0 = __float2int_rn(fabsf(v.x) * qs);
    int q1 = __float2int_rn(fabsf(v.y) * qs);
    int q2 = __float2int_rn(fabsf(v.z) * qs);
    int q3 = __float2int_rn(fabsf(v.w) * qs);
    q0 = min(max(q0, 0), 127); q1 = min(max(q1, 0), 127);
    q2 = min(max(q2, 0), 127); q3 = min(max(q3, 0), 127);
    w[k] = q0 | (q1 << 8) | (q2 << 16) | (q3 << 24);
  }

  const float alpha  = 1.0f / taus[h];          // dt = 1
  const float beta   = 1.0f - alpha;
  const float win_h  = win[h];
  const float dscale = rmax * alpha * (1.0f / 16129.0f);  // rmax/127^2 * alpha
  float s = r0[b * DHN + h];                    // x_in at t=0 is RAW r0

  for (int i = h; i < TN; i += DHN) u_lds[i] = u[b * TN + i];
  rbuf[0][h] = (signed char)__float2int_rn(sigm(s) * 127.0f);  // r for t=0

  const float* np = noise + (size_t)b * DHN + h;          // noise[t][b][h]
  float* xrow = xs + ((size_t)b * DHN + h) * TN;          // xs[b][h][t]

  // prefetch chunk 0 noise into regs
  float nreg[CH];
#pragma unroll
  for (int k = 0; k < CH; ++k) nreg[k] = np[(size_t)k * (BN * DHN)];

#pragma unroll 1
  for (int tc = 0; tc < TN; tc += CH) {
    __syncthreads();  // prev chunk's nz_lds consumed (covers init on tc==0);
                      // full drain also lands the nreg prefetch (needed now)
#pragma unroll
    for (int k = 0; k < CH; ++k) nz_lds[k * DHN + h] = nreg[k];
    __syncthreads();
    if (tc + CH < TN) {
#pragma unroll
      for (int k = 0; k < CH; ++k)        // issue next chunk's loads; they
        nreg[k] = np[(size_t)(tc + CH + k) * (BN * DHN)];  // fly under compute
    }

#pragma unroll 1
    for (int t8 = 0; t8 < CH; t8 += 8) {
      // hoist chunk-static LDS reads out of the barrier-serialized region
      float ua[8];
      *(float4*)&ua[0] = *(const float4*)&u_lds[tc + t8];
      *(float4*)&ua[4] = *(const float4*)&u_lds[tc + t8 + 4];
      float nzv[8];
#pragma unroll
      for (int e = 0; e < 8; ++e) nzv[e] = nz_lds[(t8 + e) * DHN + h];

      float xv[8];
#pragma unroll
      for (int e = 0; e < 8; ++e) {
        // t = tc + t8 + e; tc,t8 even -> t&1 == e&1 (static LDS indexing)
        // one per-lane ds_read_b64: lane l holds r-words 2l, 2l+1
        const int2 rv = *(const int2*)(&rbuf[e & 1][0] + 8 * lane);
        int a0 = 0, a1 = 0, a2 = 0, a3 = 0;
#pragma unroll
        for (int j = 0; j < 32; ++j) {
          // word 4j   -> lane 2j   .x ; word 4j+1 -> lane 2j   .y
          // word 4j+2 -> lane 2j+1 .x ; word 4j+3 -> lane 2j+1 .y
          const int rA0 = __builtin_amdgcn_readlane(rv.x, 2 * j);
          const int rB0 = __builtin_amdgcn_readlane(rv.y, 2 * j);
          const int rA1 = __builtin_amdgcn_readlane(rv.x, 2 * j + 1);
          const int rB1 = __builtin_amdgcn_readlane(rv.y, 2 * j + 1);
          a0 = dot4(w[4 * j + 0], rA0, a0);
          a1 = dot4(w[4 * j + 1], rB0, a1);
          a2 = dot4(w[4 * j + 2], rA1, a2);
          a3 = dot4(w[4 * j + 3], rB1, a3);
        }
        float x = beta * s + (float)((a0 + a1) + (a2 + a3)) * dscale
                + win_h * ua[e] + 0.1f * nzv[e];
        x = fminf(fmaxf(x, -40.0f), 40.0f);   // never binds on sane values
        xv[e] = x;
        float sp = sigm(x);                   // next x_in = sigmoid(x_new)
        rbuf[(e & 1) ^ 1][h] =
            (signed char)__float2int_rn(sigm(sp) * 127.0f);  // next r
        s = sp;
        lds_barrier();                        // lgkm-only, no vmcnt drain
      }
      float4 p0 = {xv[0], xv[1], xv[2], xv[3]};
      float4 p1 = {xv[4], xv[5], xv[6], xv[7]};
      *(float4*)(xrow + tc + t8)     = p0;    // 16B aligned
      *(float4*)(xrow + tc + t8 + 4) = p1;
    }
  }
}

// out[b,t] = bias + sum_h wout[h]*sigmoid(xs[b,h,t]); recomputed from stored
// fp32 xs (exact same values the main kernel produced).
__global__ __launch_bounds__(256) void k_out(
    const float* __restrict__ xs, const float* __restrict__ wout,
    const float* __restrict__ bias, float* __restrict__ outp) {
  __shared__ float wl[DHN];
  int b = blockIdx.x >> 2;
  int t = ((blockIdx.x & 3) << 8) | threadIdx.x;
  for (int i = threadIdx.x; i < DHN; i += 256) wl[i] = wout[i];
  __syncthreads();
  const float* col = xs + (size_t)b * DHN * TN + t;
  float acc = bias[0];
#pragma unroll 4
  for (int hh = 0; hh < DHN; ++hh)      // consecutive t across lanes: coalesced
    acc += wl[hh] * sigm(col[(size_t)hh * TN]);
  outp[b * TN + t] = acc;
}

extern "C" void kernel_launch(void* const* d_in, const int* in_sizes, int n_in,
                              void* d_out, int out_size, void* d_ws, size_t ws_size,
                              hipStream_t stream) {
  const float* u     = (const float*)d_in[0];   // (64,1024,1) fp32
  const float* r0    = (const float*)d_in[1];   // (64,512,1)  fp32
  const float* noise = (const float*)d_in[2];   // (1024,64,512,1) fp32
  const float* win   = (const float*)d_in[3];   // (512,1) fp32
  // d_in[4] = m: diag +-1, cancelled by abs() -> unused
  const float* wout  = (const float*)d_in[5];   // (1,512) fp32
  const float* w_    = (const float*)d_in[6];   // (512,512) fp32
  const float* taus  = (const float*)d_in[7];   // (512,1) fp32
  const float* bias  = (const float*)d_in[8];   // (1,1) fp32

  float* outp = (float*)d_out;              // outputs (64,1024,1) fp32
  float* xs   = outp + BN * TN;             // xs_out (64,512,1024) fp32

  k_rnn<<<BN, DHN, 0, stream>>>(u, r0, noise, win, taus, w_, xs);
  k_out<<<256, 256, 0, stream>>>(xs, wout, bias, outp);
}

// Round 2
// 1461.024 us; speedup vs baseline: 1.2644x; 1.0683x over previous
//
#include <hip/hip_runtime.h>

#define DHN 512
#define TN  1024
#define BN  64
#define CH  32      // noise-staging chunk (steps)
#define NLDSJ 12    // j in [0,NLDSJ): r-words via LDS broadcast; rest readlane

static __device__ __forceinline__ float sigm(float x) {
  return 1.0f / (1.0f + __expf(-x));
}

#if defined(__has_builtin)
#if __has_builtin(__builtin_amdgcn_sdot4)
#define HAVE_SDOT4 1
#endif
#endif

// All packed bytes are in [0,127]: signed == unsigned dot.
static __device__ __forceinline__ int dot4(int a, int b, int c) {
#ifdef HAVE_SDOT4
  return __builtin_amdgcn_sdot4(a, b, c, false);
#else
  c += (int)(signed char)(a)       * (int)(signed char)(b);
  c += (int)(signed char)(a >> 8)  * (int)(signed char)(b >> 8);
  c += (int)(signed char)(a >> 16) * (int)(signed char)(b >> 16);
  c += (int)(signed char)(a >> 24) * (int)(signed char)(b >> 24);
  return c;
#endif
}

// lgkm-only step barrier: orders the rbuf LDS producer->consumer handoff
// WITHOUT draining vmcnt (keeps noise-prefetch loads + xs stores in flight).
static __device__ __forceinline__ void lds_barrier() {
  __builtin_amdgcn_sched_barrier(0);
  asm volatile("s_waitcnt lgkmcnt(0)\n\ts_barrier" ::: "memory");
  __builtin_amdgcn_sched_barrier(0);
}

// Wave64 sum via DPP (pure VALU -- keeps the LDS pipe free). Result valid in
// lane 63 only. Classic row_shr 1/2/4/8 + row_bcast15 + row_bcast31 ladder.
#define DPPADD(x, ctrl)                                                    \
  do {                                                                     \
    int _m = __builtin_amdgcn_update_dpp(0, __builtin_bit_cast(int, (x)),  \
                                         (ctrl), 0xF, 0xF, true);          \
    (x) += __builtin_bit_cast(float, _m);                                  \
  } while (0)

static __device__ __forceinline__ float wave_sum_lane63(float x) {
  DPPADD(x, 0x111);  // row_shr:1
  DPPADD(x, 0x112);  // row_shr:2
  DPPADD(x, 0x114);  // row_shr:4
  DPPADD(x, 0x118);  // row_shr:8  -> lane 15 of each row has row sum
  DPPADD(x, 0x142);  // row_bcast:15
  DPPADD(x, 0x143);  // row_bcast:31 -> lane 63 has wave sum
  return x;
}

// Persistent RNN: one block per batch chain (64 blocks, 64 CUs). Thread h
// owns row h of W = |_w|, quantized i8 (per-row scale) into 128 VGPRs.
// r-vector distribution per step is SPLIT across two pipes so they overlap
// via 2-wave/SIMD TLP:
//   - words 4*NLDSJ..127 (20 j's): one per-lane ds_read_b64 + v_readlane
//     broadcast (VALU crossbar)
//   - words 0..4*NLDSJ-1 (12 j's): broadcast ds_read_b128 (LDS pipe,
//     otherwise idle after round-1's readlane conversion)
// Output projection out[b,t] = bias + sum_h wout[h]*sigmoid(x_new) is folded
// in via a DPP wave reduction + per-wave LDS partials (k_out deleted: saves
// a 240 us kernel that re-read 128 MB of xs).
__global__ __launch_bounds__(512) void k_rnn(
    const float* __restrict__ u, const float* __restrict__ r0,
    const float* __restrict__ noise, const float* __restrict__ win,
    const float* __restrict__ taus, const float* __restrict__ wmat,
    const float* __restrict__ wout, const float* __restrict__ bias,
    float* __restrict__ xs, float* __restrict__ outp) {
  __shared__ float u_lds[TN];                        // 4 KB
  __shared__ float nz_lds[CH * DHN];                 // 64 KB
  __shared__ __align__(16) signed char rbuf[2][DHN]; // 1 KB, i8 r dbuf
  __shared__ float part_lds[8][CH];                  // 1 KB out partials

  const int h = threadIdx.x;
  const int lane = h & 63;
  const int wv = h >> 6;
  const int b = blockIdx.x;
  const float* wrow = wmat + h * DHN;   // row h of _w (2 KB, 16B-aligned)

  // pass 1: row absmax of |_w[h,:]|
  float rmax = 1e-30f;
#pragma unroll 8
  for (int k = 0; k < 128; ++k) {
    float4 v = *(const float4*)(wrow + 4 * k);
    rmax = fmaxf(rmax, fabsf(v.x));
    rmax = fmaxf(rmax, fabsf(v.y));
    rmax = fmaxf(rmax, fabsf(v.z));
    rmax = fmaxf(rmax, fabsf(v.w));
  }
  const float qs = 127.0f / rmax;

  // pass 2: quantize row into 128 VGPRs; w[k] bytes 0..3 = |w| cols 4k..4k+3
  int w[128];
#pragma unroll
  for (int k = 0; k < 128; ++k) {
    float4 v = *(const float4*)(wrow + 4 * k);
    int q0 = __float2int_rn(fabsf(v.x) * qs);
    int q1 = __float2int_rn(fabsf(v.y) * qs);
    int q2 = __float2int_rn(fabsf(v.z) * qs);
    int q3 = __float2int_rn(fabsf(v.w) * qs);
    q0 = min(max(q0, 0), 127); q1 = min(max(q1, 0), 127);
    q2 = min(max(q2, 0), 127); q3 = min(max(q3, 0), 127);
    w[k] = q0 | (q1 << 8) | (q2 << 16) | (q3 << 24);
  }

  const float alpha  = 1.0f / taus[h];          // dt = 1
  const float beta   = 1.0f - alpha;
  const float win_h  = win[h];
  const float wout_h = wout[h];
  const float bias0  = bias[0];
  const float dscale = rmax * alpha * (1.0f / 16129.0f);  // rmax/127^2 * alpha
  float s = r0[b * DHN + h];                    // x_in at t=0 is RAW r0

  for (int i = h; i < TN; i += DHN) u_lds[i] = u[b * TN + i];
  rbuf[0][h] = (signed char)__float2int_rn(sigm(s) * 127.0f);  // r for t=0

  const float* np = noise + (size_t)b * DHN + h;          // noise[t][b][h]
  float* xrow = xs + ((size_t)b * DHN + h) * TN;          // xs[b][h][t]

  // prefetch chunk 0 noise into regs
  float nreg[CH];
#pragma unroll
  for (int k = 0; k < CH; ++k) nreg[k] = np[(size_t)k * (BN * DHN)];

#pragma unroll 1
  for (int tc = 0; tc < TN; tc += CH) {
    __syncthreads();  // prev chunk's nz_lds + part_lds consumed; full drain
                      // also lands the nreg prefetch (needed now)
    // drain previous chunk's output partials (32 threads; before sync2 so
    // part_lds can be overwritten by the new chunk's steps)
    if (tc > 0 && h < CH) {
      float o = bias0;
#pragma unroll
      for (int wq = 0; wq < 8; ++wq) o += part_lds[wq][h];
      outp[b * TN + (tc - CH) + h] = o;
    }
#pragma unroll
    for (int k = 0; k < CH; ++k) nz_lds[k * DHN + h] = nreg[k];
    __syncthreads();
    if (tc + CH < TN) {
#pragma unroll
      for (int k = 0; k < CH; ++k)        // issue next chunk's loads; they
        nreg[k] = np[(size_t)(tc + CH + k) * (BN * DHN)];  // fly under compute
    }

#pragma unroll 1
    for (int t8 = 0; t8 < CH; t8 += 8) {
      // hoist chunk-static LDS reads out of the barrier-serialized region
      float ua[8];
      *(float4*)&ua[0] = *(const float4*)&u_lds[tc + t8];
      *(float4*)&ua[4] = *(const float4*)&u_lds[tc + t8 + 4];
      float nzv[8];
#pragma unroll
      for (int e = 0; e < 8; ++e) nzv[e] = nz_lds[(t8 + e) * DHN + h];

      float xv[8];
#pragma unroll
      for (int e = 0; e < 8; ++e) {
        // t = tc + t8 + e; tc,t8 even -> t&1 == e&1 (static LDS indexing)
        const signed char* rbp = &rbuf[e & 1][0];
        // per-lane b64: lane l holds r-words 2l, 2l+1 (RL source)
        const int2 rv = *(const int2*)(rbp + 8 * lane);
        const int4* rb4 = (const int4*)rbp;
        int a0 = 0, a1 = 0, a2 = 0, a3 = 0;
        // --- LDS-broadcast section: j in [0, NLDSJ) ---
#pragma unroll
        for (int j = 0; j < NLDSJ; ++j) {
          int4 rq = rb4[j];              // broadcast ds_read_b128
          a0 = dot4(w[4 * j + 0], rq.x, a0);
          a1 = dot4(w[4 * j + 1], rq.y, a1);
          a2 = dot4(w[4 * j + 2], rq.z, a2);
          a3 = dot4(w[4 * j + 3], rq.w, a3);
        }
        // --- readlane section: j in [NLDSJ, 32) ---
#pragma unroll
        for (int j = NLDSJ; j < 32; ++j) {
          const int rA0 = __builtin_amdgcn_readlane(rv.x, 2 * j);
          const int rB0 = __builtin_amdgcn_readlane(rv.y, 2 * j);
          const int rA1 = __builtin_amdgcn_readlane(rv.x, 2 * j + 1);
          const int rB1 = __builtin_amdgcn_readlane(rv.y, 2 * j + 1);
          a0 = dot4(w[4 * j + 0], rA0, a0);
          a1 = dot4(w[4 * j + 1], rB0, a1);
          a2 = dot4(w[4 * j + 2], rA1, a2);
          a3 = dot4(w[4 * j + 3], rB1, a3);
        }
        float x = beta * s + (float)((a0 + a1) + (a2 + a3)) * dscale
                + win_h * ua[e] + 0.1f * nzv[e];
        x = fminf(fmaxf(x, -40.0f), 40.0f);   // never binds on sane values
        xv[e] = x;
        float sp = sigm(x);                   // next x_in = sigmoid(x_new)
        rbuf[(e & 1) ^ 1][h] =
            (signed char)__float2int_rn(sigm(sp) * 127.0f);  // next r
        s = sp;
        // folded output projection: out[b,t] = bias + sum_h wout[h]*sp
        float po = wave_sum_lane63(wout_h * sp);
        if (lane == 63) part_lds[wv][t8 + e] = po;
        lds_barrier();                        // lgkm-only, no vmcnt drain
      }
      float4 p0 = {xv[0], xv[1], xv[2], xv[3]};
      float4 p1 = {xv[4], xv[5], xv[6], xv[7]};
      *(float4*)(xrow + tc + t8)     = p0;    // 16B aligned
      *(float4*)(xrow + tc + t8 + 4) = p1;
    }
  }
  // drain last chunk's outputs
  __syncthreads();
  if (h < CH) {
    float o = bias0;
#pragma unroll
    for (int wq = 0; wq < 8; ++wq) o += part_lds[wq][h];
    outp[b * TN + (TN - CH) + h] = o;
  }
}

extern "C" void kernel_launch(void* const* d_in, const int* in_sizes, int n_in,
                              void* d_out, int out_size, void* d_ws, size_t ws_size,
                              hipStream_t stream) {
  const float* u     = (const float*)d_in[0];   // (64,1024,1) fp32
  const float* r0    = (const float*)d_in[1];   // (64,512,1)  fp32
  const float* noise = (const float*)d_in[2];   // (1024,64,512,1) fp32
  const float* win   = (const float*)d_in[3];   // (512,1) fp32
  // d_in[4] = m: diag +-1, cancelled by abs() -> unused
  const float* wout  = (const float*)d_in[5];   // (1,512) fp32
  const float* w_    = (const float*)d_in[6];   // (512,512) fp32
  const float* taus  = (const float*)d_in[7];   // (512,1) fp32
  const float* bias  = (const float*)d_in[8];   // (1,1) fp32

  float* outp = (float*)d_out;              // outputs (64,1024,1) fp32
  float* xs   = outp + BN * TN;             // xs_out (64,512,1024) fp32

  k_rnn<<<BN, DHN, 0, stream>>>(u, r0, noise, win, taus, w_, wout, bias,
                                xs, outp);
}

// Round 3
// 1234.439 us; speedup vs baseline: 1.4965x; 1.1836x over previous
//
#include <hip/hip_runtime.h>

#define DHN 512
#define TN  1024
#define BN  64
#define CH  16      // noise-staging chunk (steps)

typedef int int4v __attribute__((ext_vector_type(4)));

static __device__ __forceinline__ float sigm(float x) {
  return 1.0f / (1.0f + __expf(-x));
}

// lgkm-only step barrier: orders the rbuf LDS producer->consumer handoff
// WITHOUT draining vmcnt (keeps noise-prefetch loads + xs stores in flight).
static __device__ __forceinline__ void lds_barrier() {
  __builtin_amdgcn_sched_barrier(0);
  asm volatile("s_waitcnt lgkmcnt(0)\n\ts_barrier" ::: "memory");
  __builtin_amdgcn_sched_barrier(0);
}

// Wave64 sum via DPP (pure VALU). Result valid in lane 63 only.
#define DPPADD(x, ctrl)                                                    \
  do {                                                                     \
    int _m = __builtin_amdgcn_update_dpp(0, __builtin_bit_cast(int, (x)),  \
                                         (ctrl), 0xF, 0xF, true);          \
    (x) += __builtin_bit_cast(float, _m);                                  \
  } while (0)

static __device__ __forceinline__ float wave_sum_lane63(float x) {
  DPPADD(x, 0x111);  // row_shr:1
  DPPADD(x, 0x112);  // row_shr:2
  DPPADD(x, 0x114);  // row_shr:4
  DPPADD(x, 0x118);  // row_shr:8  -> lane 15 of each row has row sum
  DPPADD(x, 0x142);  // row_bcast:15
  DPPADD(x, 0x143);  // row_bcast:31 -> lane 63 has wave sum
  return x;
}

// Persistent RNN, one block per batch chain (64 blocks / 64 CUs).
// Round-3 change: the 512x512 i8 matvec moves from v_dot4 (VALU, measured
// ~2200 cyc/SIMD/step) to the idle MFMA pipe as 256x mfma_i32_16x16x64_i8
// per CU per step (~1300 MFMA-pipe cyc). i32 accumulation is order-exact,
// so x values are bitwise identical to the dot4 version.
//
// Fragment layouts for v_mfma_i32_16x16x64_i8 (std CDNA mapping; C/D part
// HW-verified per guide m89):
//   A (16x64): row = lane&15,        k = 16*(lane>>4) + byte(0..15)
//   B (64x16): col = lane&15,        k = 16*(lane>>4) + byte(0..15)
//   D (16x16): col = lane&15,        row = 4*(lane>>4) + reg(0..3)
// B is fed the same r-bytes in every col group (addr independent of
// lane&15) -> D replicated across cols; we consume col 0 (lanes&15==0).
// Wave w owns M-tiles 4w..4w+3 = rows 64w..64w+63 = exactly its own
// threads' rows, so D->owner redistribution is WITHIN-WAVE via a 64-dword
// LDS region + lgkmcnt (no extra barrier; still 1 barrier/step).
__global__ __launch_bounds__(512, 2) void k_rnn(
    const float* __restrict__ u, const float* __restrict__ r0,
    const float* __restrict__ noise, const float* __restrict__ win,
    const float* __restrict__ taus, const float* __restrict__ wmat,
    const float* __restrict__ wout, const float* __restrict__ bias,
    float* __restrict__ xs, float* __restrict__ outp) {
  __shared__ float u_lds[TN];                        // 4 KB
  __shared__ float nz_lds[CH * DHN];                 // 32 KB
  __shared__ __align__(16) signed char rbuf[2][DHN]; // 1 KB, i8 r dbuf
  __shared__ float part_lds[8][CH];                  // out partials
  __shared__ __align__(16) int dsum[DHN];            // 2 KB, per-wave 64 dw
  __shared__ float qs_lds[DHN];                      // 2 KB row quant scales

  const int h    = threadIdx.x;
  const int lane = h & 63;
  const int wv   = h >> 6;
  const int lrow = lane & 15;   // A-row within tile / D col
  const int lkg  = lane >> 4;   // k-group (16 bytes each)
  const int b    = blockIdx.x;
  const float* wrow = wmat + h * DHN;   // row h of _w

  // pass 1: row absmax of |_w[h,:]| (thread h owns row h's scale)
  float rmax = 1e-30f;
#pragma unroll 8
  for (int k = 0; k < 128; ++k) {
    float4 v = *(const float4*)(wrow + 4 * k);
    rmax = fmaxf(rmax, fabsf(v.x));
    rmax = fmaxf(rmax, fabsf(v.y));
    rmax = fmaxf(rmax, fabsf(v.z));
    rmax = fmaxf(rmax, fabsf(v.w));
  }
  const float qs = 127.0f / rmax;
  qs_lds[h] = qs;

  const float alpha  = 1.0f / taus[h];          // dt = 1
  const float beta   = 1.0f - alpha;
  const float win_h  = win[h];
  const float wout_h = wout[h];
  const float bias0  = bias[0];
  const float dscale = rmax * alpha * (1.0f / 16129.0f);  // rmax/127^2 * alpha
  float s = r0[b * DHN + h];                    // x_in at t=0 is RAW r0

  for (int i = h; i < TN; i += DHN) u_lds[i] = u[b * TN + i];
  rbuf[0][h] = (signed char)__float2int_rn(sigm(s) * 127.0f);  // r for t=0

  __syncthreads();  // qs_lds ready for fragment quantization

  // pass 2: load + quantize A-fragments. wfrag[m][q]: lane holds
  // W[16*(4wv+m) + lrow][64q + 16*lkg .. +15] as i8, scale qs_lds[row].
  // Byte i (LSB-first within dwords) = k offset i: identical packing to
  // the dot4 kernel -> identical quantized bytes -> identical i32 dots.
  int4v wfrag[4][8];
#pragma unroll
  for (int m = 0; m < 4; ++m) {
    const int row = (wv * 4 + m) * 16 + lrow;
    const float qsr = qs_lds[row];
    const float* rp = wmat + (size_t)row * DHN + lkg * 16;
#pragma unroll
    for (int q = 0; q < 8; ++q) {
      const float* cp = rp + q * 64;
      int4v wd;
#pragma unroll
      for (int d = 0; d < 4; ++d) {
        float4 v = *(const float4*)(cp + 4 * d);
        int q0 = min(max(__float2int_rn(fabsf(v.x) * qsr), 0), 127);
        int q1 = min(max(__float2int_rn(fabsf(v.y) * qsr), 0), 127);
        int q2 = min(max(__float2int_rn(fabsf(v.z) * qsr), 0), 127);
        int q3 = min(max(__float2int_rn(fabsf(v.w) * qsr), 0), 127);
        wd[d] = q0 | (q1 << 8) | (q2 << 16) | (q3 << 24);
      }
      wfrag[m][q] = wd;
    }
  }

  const float* np = noise + (size_t)b * DHN + h;          // noise[t][b][h]
  float* xrow = xs + ((size_t)b * DHN + h) * TN;          // xs[b][h][t]

  // prefetch chunk 0 noise into regs
  float nreg[CH];
#pragma unroll
  for (int k = 0; k < CH; ++k) nreg[k] = np[(size_t)k * (BN * DHN)];

#pragma unroll 1
  for (int tc = 0; tc < TN; tc += CH) {
    __syncthreads();  // prev chunk's nz_lds/part_lds consumed; drains the
                      // nreg prefetch (needed now)
    if (tc > 0 && h < CH) {  // drain previous chunk's output partials
      float o = bias0;
#pragma unroll
      for (int wq = 0; wq < 8; ++wq) o += part_lds[wq][h];
      outp[b * TN + (tc - CH) + h] = o;
    }
#pragma unroll
    for (int k = 0; k < CH; ++k) nz_lds[k * DHN + h] = nreg[k];
    __syncthreads();
    if (tc + CH < TN) {
#pragma unroll
      for (int k = 0; k < CH; ++k)        // next chunk's loads fly under
        nreg[k] = np[(size_t)(tc + CH + k) * (BN * DHN)];  // compute
    }

#pragma unroll 1
    for (int t8 = 0; t8 < CH; t8 += 8) {
      // hoist chunk-static LDS reads out of the barrier-serialized region
      float ua[8];
      *(float4*)&ua[0] = *(const float4*)&u_lds[tc + t8];
      *(float4*)&ua[4] = *(const float4*)&u_lds[tc + t8 + 4];
      float nzv[8];
#pragma unroll
      for (int e = 0; e < 8; ++e) nzv[e] = nz_lds[(t8 + e) * DHN + h];

      float xv[8];
#pragma unroll
      for (int e = 0; e < 8; ++e) {
        // t = tc + t8 + e; tc,t8 even -> t&1 == e&1 (static LDS indexing)
        const signed char* rbp = &rbuf[e & 1][0];
        // B fragments: addr = 64q + 16*lkg, independent of lrow ->
        // 4 distinct 16B lines per wave, 16-lane broadcast each.
        int4v bq[8];
#pragma unroll
        for (int q = 0; q < 8; ++q)
          bq[q] = *(const int4v*)(rbp + q * 64 + lkg * 16);

        const int4v zz = {0, 0, 0, 0};
        int4v acc[4];
#pragma unroll
        for (int m = 0; m < 4; ++m) acc[m] = zz;
#pragma unroll
        for (int q = 0; q < 8; ++q) {
#pragma unroll
          for (int m = 0; m < 4; ++m)
            acc[m] = __builtin_amdgcn_mfma_i32_16x16x64_i8(
                wfrag[m][q], bq[q], acc[m], 0, 0, 0);
        }
        // within-wave redistribution: col-0 lanes scatter D rows to the
        // wave's private 64-dword dsum region; owner reads its dword.
        // dword (64wv + 16m + 4*lkg + reg) = D[tile 4wv+m][row 4*lkg+reg]
        // -> thread h reads dsum[h] = dot(row h). Compiler inserts the
        // lgkmcnt wait for the write->read dependency (same wave).
        if (lrow == 0) {
#pragma unroll
          for (int m = 0; m < 4; ++m)
            *(int4v*)&dsum[wv * 64 + m * 16 + lkg * 4] = acc[m];
        }
        const int dot = dsum[h];
        float x = beta * s + (float)dot * dscale
                + win_h * ua[e] + 0.1f * nzv[e];
        x = fminf(fmaxf(x, -40.0f), 40.0f);   // never binds on sane values
        xv[e] = x;
        float sp = sigm(x);                   // next x_in = sigmoid(x_new)
        rbuf[(e & 1) ^ 1][h] =
            (signed char)__float2int_rn(sigm(sp) * 127.0f);  // next r
        s = sp;
        // folded output projection: out[b,t] = bias + sum_h wout[h]*sp
        float po = wave_sum_lane63(wout_h * sp);
        if (lane == 63) part_lds[wv][t8 + e] = po;
        lds_barrier();                        // lgkm-only, no vmcnt drain
      }
      float4 p0 = {xv[0], xv[1], xv[2], xv[3]};
      float4 p1 = {xv[4], xv[5], xv[6], xv[7]};
      *(float4*)(xrow + tc + t8)     = p0;    // 16B aligned
      *(float4*)(xrow + tc + t8 + 4) = p1;
    }
  }
  // drain last chunk's outputs
  __syncthreads();
  if (h < CH) {
    float o = bias0;
#pragma unroll
    for (int wq = 0; wq < 8; ++wq) o += part_lds[wq][h];
    outp[b * TN + (TN - CH) + h] = o;
  }
}

extern "C" void kernel_launch(void* const* d_in, const int* in_sizes, int n_in,
                              void* d_out, int out_size, void* d_ws, size_t ws_size,
                              hipStream_t stream) {
  const float* u     = (const float*)d_in[0];   // (64,1024,1) fp32
  const float* r0    = (const float*)d_in[1];   // (64,512,1)  fp32
  const float* noise = (const float*)d_in[2];   // (1024,64,512,1) fp32
  const float* win   = (const float*)d_in[3];   // (512,1) fp32
  // d_in[4] = m: diag +-1, cancelled by abs() -> unused
  const float* wout  = (const float*)d_in[5];   // (1,512) fp32
  const float* w_    = (const float*)d_in[6];   // (512,512) fp32
  const float* taus  = (const float*)d_in[7];   // (512,1) fp32
  const float* bias  = (const float*)d_in[8];   // (1,1) fp32

  float* outp = (float*)d_out;              // outputs (64,1024,1) fp32
  float* xs   = outp + BN * TN;             // xs_out (64,512,1024) fp32

  k_rnn<<<BN, DHN, 0, stream>>>(u, r0, noise, win, taus, w_, wout, bias,
                                xs, outp);
}